// Round 8
// baseline (60.187 us; speedup 1.0000x reference)
//
#include <hip/hip_runtime.h>
#include <hip/hip_cooperative_groups.h>

namespace cg = cooperative_groups;

#define CAP  32     // bucket capacity (lambda ~ 4 tokens/cell; P(overflow) ~ 1e-17)
#define MAXC 1024   // supports gs <= 32 (test: gs = 32); gs >= 4 assumed for wrap

__device__ __forceinline__ float fpow_pos(float x, float p) {
    // x >= 0; pow via hardware log2/exp2. x==0 -> log2=-inf -> exp2(-inf)=0 (p>0).
    return __builtin_exp2f(p * __builtin_log2f(x));
}

// Single fused cooperative kernel:
//   Phase A: zero cell counters         (tid < MAXC)
//   Phase B: bucket build, 1 thr/token  (tid < n)
//   Phase C: forces, 8 lanes/receiver   (tid < 8n), width-8 reduce, direct store
// No early returns before the grid syncs — every thread reaches both barriers.
__global__ __launch_bounds__(256) void gwave_fused(
    const float* __restrict__ ell, const float* __restrict__ theta,
    const float* __restrict__ fs, const float* __restrict__ mass,
    const unsigned char* __restrict__ frozen,
    const int* __restrict__ gsize_p, int n,
    int* __restrict__ counts, float4* __restrict__ buck,
    float* __restrict__ out)
{
    const float PHI       = 1.61803398875f;
    const float INV_PHI   = 0.61803398875f;
    const float ONE_P_PHI = 2.61803398875f;
    const float TAU  = 6.2831855f;         // float32(2*pi)
    const float PI_F = 3.14159274f;        // float32(pi)
    const float EPS  = 1e-10f;

    cg::grid_group grid = cg::this_grid();
    const int tid = blockIdx.x * 256 + threadIdx.x;

    const int gs = *gsize_p;
    const float cw_ell = 2.0f / (float)gs;
    const float cw_th  = TAU  / (float)gs;

    // ---- Phase A: zero cell counters ----
    if (tid < MAXC) counts[tid] = 0;
    grid.sync();

    // ---- Phase B: bucket build ----
    if (tid < n && !frozen[tid]) {
        const float e = ell[tid], t = theta[tid];
        int ce = min(max((int)floorf(e / cw_ell), 0), gs - 1);
        float tw = t - floorf(t / TAU) * TAU;   // jnp.mod(theta, TAU)
        int ct = min(max((int)floorf(tw / cw_th), 0), gs - 1);
        const int c = ce * gs + ct;
        int pos = atomicAdd(&counts[c], 1);
        if (pos < CAP)
            buck[c * CAP + pos] = make_float4(e, t, fs[tid], __int_as_float(tid));
    }
    grid.sync();

    // ---- Phase C: forces ----
    const int i = tid >> 3;                // receiver token
    const int r = tid & 7;                 // lane within 8-group
    if (i < n) {
        float Fe = 0.f, Ft = 0.f;
        if (!frozen[i]) {
            const float e_i = ell[i], t_i = theta[i];
            const float f_i = fs[i],  m_i = mass[i];
            int ce_i = min(max((int)floorf(e_i / cw_ell), 0), gs - 1);
            float tw = t_i - floorf(t_i / TAU) * TAU;
            int ct_i = min(max((int)floorf(tw / cw_th), 0), gs - 1);
            const float tp = PI_F - t_i;

            for (int k = r; k < 9; k += 8) {   // lane r: cell r; lane 0 also cell 8
                int kdiv = (k >= 6) ? 2 : (k >= 3 ? 1 : 0);
                int ce = ce_i + kdiv - 1;      // ell cells do NOT wrap
                if (ce < 0 || ce >= gs) continue;
                int ct = ct_i + (k - kdiv * 3) - 1;
                if (ct < 0) ct += gs; else if (ct >= gs) ct -= gs;
                const int c = ce * gs + ct;

                const int cnt = min(counts[c], CAP);
                const float4* bp = buck + c * CAP;
                for (int j = 0; j < cnt; ++j) {
                    float4 o = bp[j];
                    int jdx = __float_as_int(o.w);
                    float dl = o.x - e_i;
                    // jnp.mod(dtheta+pi, tau)-pi; masked pairs never sit at the
                    // 0/tau rounding boundary (|dtheta| <= 2 cells), so the
                    // predicated wrap equals floor-mod.
                    float x = o.y + tp;        // in (-pi, 3pi)
                    x += (x < 0.f)  ? TAU : 0.f;
                    x -= (x >= TAU) ? TAU : 0.f;
                    float dt = x - PI_F;

                    float inner = fpow_pos(fabsf(dl), PHI) + fpow_pos(fabsf(dt), PHI);
                    float dL = fpow_pos(inner, INV_PHI) + EPS;
                    float fm = __fdividef(f_i * o.z,
                                          fpow_pos(dL, ONE_P_PHI) * m_i + EPS);
                    float w = fm * __fdividef(1.f, dL);
                    bool keep = (jdx != i);    // self-exclusion
                    Fe += keep ? w * dl : 0.f;
                    Ft += keep ? w * dt : 0.f;
                }
            }
        }

        // width-8 butterfly reduce (8-lane groups are exec-uniform: i is
        // constant across each group, so all 8 lanes are active together)
        Fe += __shfl_xor(Fe, 1);
        Ft += __shfl_xor(Ft, 1);
        Fe += __shfl_xor(Fe, 2);
        Ft += __shfl_xor(Ft, 2);
        Fe += __shfl_xor(Fe, 4);
        Ft += __shfl_xor(Ft, 4);

        if (r == 0) {                      // frozen receivers store 0
            out[i]     = Fe;
            out[n + i] = Ft;
        }
    }
}

extern "C" void kernel_launch(void* const* d_in, const int* in_sizes, int n_in,
                              void* d_out, int out_size, void* d_ws, size_t ws_size,
                              hipStream_t stream) {
    const float* ell   = (const float*)d_in[0];
    const float* theta = (const float*)d_in[1];
    const float* fs    = (const float*)d_in[2];
    const float* mass  = (const float*)d_in[3];
    const unsigned char* frozen = (const unsigned char*)d_in[4];
    const int* gsize   = (const int*)d_in[5];
    float* out = (float*)d_out;
    int n = in_sizes[0];

    // ws: counts = MAXC ints (4 KB), then buck[MAXC*CAP] float4 (512 KB)
    int*    counts = (int*)d_ws;
    float4* buck   = (float4*)((char*)d_ws + MAXC * sizeof(int));

    int nthreads = 8 * n;
    if (nthreads < MAXC) nthreads = MAXC;
    int blocks = (nthreads + 255) / 256;   // 128 blocks at n=4096 — co-resident

    void* args[] = {
        (void*)&ell, (void*)&theta, (void*)&fs, (void*)&mass,
        (void*)&frozen, (void*)&gsize, (void*)&n,
        (void*)&counts, (void*)&buck, (void*)&out
    };
    (void)hipLaunchCooperativeKernel((const void*)gwave_fused,
                                     dim3(blocks), dim3(256),
                                     args, 0, stream);
}

// Round 9
// 26.785 us; speedup vs baseline: 2.2470x; 2.2470x over previous
//
#include <hip/hip_runtime.h>

#define TPB  1024
#define RPB  (TPB / 8)      // receivers per block (8 lanes each) = 128
#define NMAX 4096           // max tokens supported by the LDS sort (test: N=4096)
#define MAXC 1024           // max cells (gs <= 32; test gs = 32); gs >= 4 for wrap

__device__ __forceinline__ float fpow_pos(float x, float p) {
    // x >= 0; pow via hardware log2/exp2. x==0 -> log2=-inf -> exp2(-inf)=0 (p>0).
    return __builtin_exp2f(p * __builtin_log2f(x));
}

// ONE regular kernel, no cross-block dependencies (R8 lesson: grid.sync via
// cooperative launch is pathological here; R6/R7 lesson: every extra graph
// node costs us ~2-5 us). Each block redundantly counting-sorts ALL tokens
// into its own LDS (60 KB), then computes forces for its 128 receivers from
// LDS. Receivers are mapped by GLOBAL token index, so differing intra-cell
// scatter order across blocks cannot change coverage or results (each active
// token appears exactly once in every block's sorted array).
__global__ __launch_bounds__(TPB) void gwave_fused(
    const float* __restrict__ ell, const float* __restrict__ theta,
    const float* __restrict__ fs, const float* __restrict__ mass,
    const unsigned char* __restrict__ frozen,
    const int* __restrict__ gsize_p, int n,
    float* __restrict__ out)
{
    __shared__ float s_e[NMAX];            // 16 KB
    __shared__ float s_t[NMAX];            // 16 KB
    __shared__ float s_f[NMAX];            // 16 KB
    __shared__ unsigned short s_idx[NMAX]; //  8 KB
    __shared__ int s_start[MAXC];          //  4 KB  (counts -> starts -> ends)
    __shared__ int s_wsum[TPB / 64];

    const float PHI       = 1.61803398875f;
    const float INV_PHI   = 0.61803398875f;
    const float ONE_P_PHI = 2.61803398875f;
    const float TAU  = 6.2831855f;         // float32(2*pi)
    const float PI_F = 3.14159274f;        // float32(pi)
    const float EPS  = 1e-10f;

    const int tid  = threadIdx.x;
    const int lane = tid & 63;
    const int wid  = tid >> 6;
    const int gs = *gsize_p;
    const int C = gs * gs;                 // <= MAXC
    const float cw_ell = 2.0f / (float)gs;
    const float cw_th  = TAU  / (float)gs;

    // ---- Phase A: zero cell counters ----
    for (int c = tid; c < C; c += TPB) s_start[c] = 0;
    __syncthreads();

    // ---- Phase B1: load tokens (4/thread), histogram; zero frozen outputs ----
    float re[4], rt[4], rf[4];
    int   rc[4];
    #pragma unroll
    for (int k = 0; k < 4; ++k) {
        rc[k] = -1;
        const int r = tid + k * TPB;
        if (r < n) {
            const float e = ell[r], t = theta[r];
            if (frozen[r]) {
                out[r] = 0.f; out[n + r] = 0.f;   // all blocks write 0: benign
            } else {
                int ce = min(max((int)floorf(e / cw_ell), 0), gs - 1);
                float tw = t - floorf(t / TAU) * TAU;   // jnp.mod(theta, TAU)
                int ct = min(max((int)floorf(tw / cw_th), 0), gs - 1);
                const int c = ce * gs + ct;
                re[k] = e; rt[k] = t; rf[k] = fs[r]; rc[k] = c;
                atomicAdd(&s_start[c], 1);
            }
        }
    }
    __syncthreads();

    // ---- Phase B2: exclusive scan of cell counts (shuffle-based) ----
    const int cnt = (tid < C) ? s_start[tid] : 0;
    int v = cnt;
    #pragma unroll
    for (int d = 1; d < 64; d <<= 1) {
        int u = __shfl_up(v, d, 64);
        if (lane >= d) v += u;
    }
    if (lane == 63) s_wsum[wid] = v;
    __syncthreads();
    if (wid == 0) {
        int w = (lane < TPB / 64) ? s_wsum[lane] : 0;
        #pragma unroll
        for (int d = 1; d < TPB / 64; d <<= 1) {
            int u = __shfl_up(w, d, 64);
            if (lane >= d) w += u;
        }
        if (lane < TPB / 64) s_wsum[lane] = w;
    }
    __syncthreads();
    const int excl = v - cnt + ((wid > 0) ? s_wsum[wid - 1] : 0);
    if (tid < C) s_start[tid] = excl;      // safe: only thread tid read cell tid
    __syncthreads();

    // ---- Phase B3: scatter into sorted SoA (cursor = s_start, becomes ends) ----
    #pragma unroll
    for (int k = 0; k < 4; ++k) {
        if (rc[k] >= 0) {
            const int pos = atomicAdd(&s_start[rc[k]], 1);
            s_e[pos] = re[k];
            s_t[pos] = rt[k];
            s_f[pos] = rf[k];
            s_idx[pos] = (unsigned short)(tid + k * TPB);
        }
    }
    __syncthreads();
    // Now s_start[c] = end(c); start(c) = (c > 0) ? s_start[c-1] : 0.

    // ---- Phase C: forces for this block's 128 receivers, 8 lanes each ----
    const int i  = blockIdx.x * RPB + (tid >> 3);   // global receiver index
    const int r8 = tid & 7;
    if (i < n) {
        float Fe = 0.f, Ft = 0.f;
        if (!frozen[i]) {
            const float e_i = ell[i], t_i = theta[i];
            const float f_i = fs[i],  m_i = mass[i];
            int ce_i = min(max((int)floorf(e_i / cw_ell), 0), gs - 1);
            float tw = t_i - floorf(t_i / TAU) * TAU;
            int ct_i = min(max((int)floorf(tw / cw_th), 0), gs - 1);
            const float tp = PI_F - t_i;
            const unsigned short me = (unsigned short)i;

            for (int k = r8; k < 9; k += 8) {  // lane r: cell r; lane 0 also 8
                const int kdiv = (k >= 6) ? 2 : (k >= 3 ? 1 : 0);
                const int ce = ce_i + kdiv - 1;        // ell cells do NOT wrap
                if (ce < 0 || ce >= gs) continue;
                int ct = ct_i + (k - kdiv * 3) - 1;    // theta cells wrap
                if (ct < 0) ct += gs; else if (ct >= gs) ct -= gs;
                const int c = ce * gs + ct;

                const int q0 = (c > 0) ? s_start[c - 1] : 0;
                const int q1 = s_start[c];
                for (int q = q0; q < q1; ++q) {
                    const float dl = s_e[q] - e_i;
                    // jnp.mod(dtheta+pi, tau)-pi; masked pairs never sit at
                    // the 0/tau rounding boundary (|dtheta| <= 2 cells), so
                    // the predicated wrap equals floor-mod.
                    float x = s_t[q] + tp;             // in (-pi, 3pi)
                    x += (x < 0.f)  ? TAU : 0.f;
                    x -= (x >= TAU) ? TAU : 0.f;
                    const float dt = x - PI_F;

                    const float inner = fpow_pos(fabsf(dl), PHI)
                                      + fpow_pos(fabsf(dt), PHI);
                    const float dL = fpow_pos(inner, INV_PHI) + EPS;
                    const float fm = __fdividef(f_i * s_f[q],
                                        fpow_pos(dL, ONE_P_PHI) * m_i + EPS);
                    const float w = fm * __fdividef(1.f, dL);
                    const bool keep = (s_idx[q] != me);   // self-exclusion
                    Fe += keep ? w * dl : 0.f;
                    Ft += keep ? w * dt : 0.f;
                }
            }
        }

        // width-8 butterfly reduce (i is uniform within each 8-lane group)
        Fe += __shfl_xor(Fe, 1);
        Ft += __shfl_xor(Ft, 1);
        Fe += __shfl_xor(Fe, 2);
        Ft += __shfl_xor(Ft, 2);
        Fe += __shfl_xor(Fe, 4);
        Ft += __shfl_xor(Ft, 4);

        if (r8 == 0) {                     // frozen receivers store 0 (match B1)
            out[i]     = Fe;
            out[n + i] = Ft;
        }
    }
}

extern "C" void kernel_launch(void* const* d_in, const int* in_sizes, int n_in,
                              void* d_out, int out_size, void* d_ws, size_t ws_size,
                              hipStream_t stream) {
    const float* ell   = (const float*)d_in[0];
    const float* theta = (const float*)d_in[1];
    const float* fs    = (const float*)d_in[2];
    const float* mass  = (const float*)d_in[3];
    const unsigned char* frozen = (const unsigned char*)d_in[4];
    const int* gsize   = (const int*)d_in[5];
    float* out = (float*)d_out;
    const int n = in_sizes[0];             // assumed <= NMAX (test: 4096)

    const int blocks = (n + RPB - 1) / RPB;   // 32 at n=4096
    gwave_fused<<<blocks, TPB, 0, stream>>>(
        ell, theta, fs, mass, frozen, gsize, n, out);
}

// Round 10
// 18.123 us; speedup vs baseline: 3.3210x; 1.4780x over previous
//
#include <hip/hip_runtime.h>

#define TPB  1024
#define RPB  32             // receivers per block (32 lanes each)
#define NMAX 4096           // max tokens supported by the LDS sort (test: N=4096)
#define MAXC 1024           // max cells (gs <= 32; test gs = 32); gs >= 4 for wrap

__device__ __forceinline__ float fpow_pos(float x, float p) {
    // x >= 0; pow via hardware log2/exp2. x==0 -> log2=-inf -> exp2(-inf)=0 (p>0).
    return __builtin_exp2f(p * __builtin_log2f(x));
}

// ONE kernel, no cross-block deps. 128 blocks (vs R9's 32 — use the whole
// chip). Each block counting-sorts ALL tokens into LDS (vectorized loads,
// shuffle scan), then computes its 32 receivers with 32 LANES each: every
// neighbor cell is one parallel step (occupancy ~4 <= 32 lanes), so the
// serial critical path is ~9 transcendental chains, divergence-free.
__global__ __launch_bounds__(TPB) void gwave_fused(
    const float* __restrict__ ell, const float* __restrict__ theta,
    const float* __restrict__ fs, const float* __restrict__ mass,
    const unsigned char* __restrict__ frozen,
    const int* __restrict__ gsize_p, int n,
    float* __restrict__ out)
{
    __shared__ float s_e[NMAX];            // 16 KB
    __shared__ float s_t[NMAX];            // 16 KB
    __shared__ float s_f[NMAX];            // 16 KB
    __shared__ unsigned short s_idx[NMAX]; //  8 KB
    __shared__ int s_start[MAXC];          //  4 KB  (counts -> ends)
    __shared__ int s_wsum[TPB / 64];

    const float PHI       = 1.61803398875f;
    const float INV_PHI   = 0.61803398875f;
    const float ONE_P_PHI = 2.61803398875f;
    const float TAU  = 6.2831855f;         // float32(2*pi)
    const float PI_F = 3.14159274f;        // float32(pi)
    const float EPS  = 1e-10f;

    const int tid  = threadIdx.x;
    const int lane = tid & 63;
    const int wid  = tid >> 6;
    const int gs = *gsize_p;
    const int C = gs * gs;                 // <= MAXC
    const float cw_ell = 2.0f / (float)gs;
    const float cw_th  = TAU  / (float)gs;

    // ---- Phase A: zero cell counters ----
    for (int c = tid; c < C; c += TPB) s_start[c] = 0;
    __syncthreads();

    // ---- Phase B1: vectorized load of 4 contiguous tokens/thread + histogram ----
    float re[4], rt[4], rf[4];
    int   rc[4];
    rc[0] = rc[1] = rc[2] = rc[3] = -1;
    const int base = tid << 2;
    if (base + 3 < n) {
        const float4 e4 = ((const float4*)ell)[tid];
        const float4 t4 = ((const float4*)theta)[tid];
        const float4 f4 = ((const float4*)fs)[tid];
        const uchar4 z4 = ((const uchar4*)frozen)[tid];
        re[0]=e4.x; re[1]=e4.y; re[2]=e4.z; re[3]=e4.w;
        rt[0]=t4.x; rt[1]=t4.y; rt[2]=t4.z; rt[3]=t4.w;
        rf[0]=f4.x; rf[1]=f4.y; rf[2]=f4.z; rf[3]=f4.w;
        const unsigned char zz[4] = {z4.x, z4.y, z4.z, z4.w};
        #pragma unroll
        for (int k = 0; k < 4; ++k) {
            if (!zz[k]) {
                int ce = min(max((int)floorf(re[k] / cw_ell), 0), gs - 1);
                float tw = rt[k] - floorf(rt[k] / TAU) * TAU;  // jnp.mod(theta,TAU)
                int ct = min(max((int)floorf(tw / cw_th), 0), gs - 1);
                rc[k] = ce * gs + ct;
                atomicAdd(&s_start[rc[k]], 1);
            }
        }
    } else {
        #pragma unroll
        for (int k = 0; k < 4; ++k) {      // scalar tail (n not multiple of 4)
            const int r = base + k;
            if (r < n && !frozen[r]) {
                re[k] = ell[r]; rt[k] = theta[r]; rf[k] = fs[r];
                int ce = min(max((int)floorf(re[k] / cw_ell), 0), gs - 1);
                float tw = rt[k] - floorf(rt[k] / TAU) * TAU;
                int ct = min(max((int)floorf(tw / cw_th), 0), gs - 1);
                rc[k] = ce * gs + ct;
                atomicAdd(&s_start[rc[k]], 1);
            }
        }
    }
    __syncthreads();

    // ---- Phase B2: exclusive scan of cell counts (shuffle-based) ----
    const int cnt = (tid < C) ? s_start[tid] : 0;
    int v = cnt;
    #pragma unroll
    for (int d = 1; d < 64; d <<= 1) {
        int u = __shfl_up(v, d, 64);
        if (lane >= d) v += u;
    }
    if (lane == 63) s_wsum[wid] = v;
    __syncthreads();
    if (wid == 0) {
        int w = (lane < TPB / 64) ? s_wsum[lane] : 0;
        #pragma unroll
        for (int d = 1; d < TPB / 64; d <<= 1) {
            int u = __shfl_up(w, d, 64);
            if (lane >= d) w += u;
        }
        if (lane < TPB / 64) s_wsum[lane] = w;
    }
    __syncthreads();
    const int excl = v - cnt + ((wid > 0) ? s_wsum[wid - 1] : 0);
    if (tid < C) s_start[tid] = excl;      // only thread tid reads cell tid
    __syncthreads();

    // ---- Phase B3: scatter (cursor = s_start, becomes ends) ----
    #pragma unroll
    for (int k = 0; k < 4; ++k) {
        if (rc[k] >= 0) {
            const int pos = atomicAdd(&s_start[rc[k]], 1);
            s_e[pos] = re[k];
            s_t[pos] = rt[k];
            s_f[pos] = rf[k];
            s_idx[pos] = (unsigned short)(base + k);
        }
    }
    __syncthreads();
    // s_start[c] = end(c); start(c) = (c > 0) ? s_start[c-1] : 0.

    // ---- Phase C: 32 receivers/block, 32 lanes each ----
    const int i   = blockIdx.x * RPB + (tid >> 5);  // global receiver index
    const int l32 = tid & 31;
    if (i < n) {
        float Fe = 0.f, Ft = 0.f;
        if (!frozen[i]) {
            const float e_i = ell[i], t_i = theta[i];
            const float f_i = fs[i],  m_i = mass[i];
            int ce_i = min(max((int)floorf(e_i / cw_ell), 0), gs - 1);
            float tw = t_i - floorf(t_i / TAU) * TAU;
            int ct_i = min(max((int)floorf(tw / cw_th), 0), gs - 1);
            const float tp = PI_F - t_i;
            const unsigned short me = (unsigned short)i;

            #pragma unroll
            for (int k = 0; k < 9; ++k) {  // each cell: ONE parallel lane-step
                const int kdiv = k / 3;                // 0,1,2 (unrolled consts)
                const int ce = ce_i + kdiv - 1;        // ell cells do NOT wrap
                if (ce < 0 || ce >= gs) continue;
                int ct = ct_i + (k - kdiv * 3) - 1;    // theta cells wrap
                if (ct < 0) ct += gs; else if (ct >= gs) ct -= gs;
                const int c = ce * gs + ct;

                const int q0 = (c > 0) ? s_start[c - 1] : 0;
                const int q1 = s_start[c];
                for (int q = q0 + l32; q < q1; q += 32) {
                    const float dl = s_e[q] - e_i;
                    // jnp.mod(dtheta+pi, tau)-pi; masked pairs never sit at
                    // the 0/tau rounding boundary (|dtheta| <= 2 cells), so
                    // the predicated wrap equals floor-mod.
                    float x = s_t[q] + tp;             // in (-pi, 3pi)
                    x += (x < 0.f)  ? TAU : 0.f;
                    x -= (x >= TAU) ? TAU : 0.f;
                    const float dt = x - PI_F;

                    const float inner = fpow_pos(fabsf(dl), PHI)
                                      + fpow_pos(fabsf(dt), PHI);
                    const float dL = fpow_pos(inner, INV_PHI) + EPS;
                    const float fm = __fdividef(f_i * s_f[q],
                                        fpow_pos(dL, ONE_P_PHI) * m_i + EPS);
                    const float w = fm * __fdividef(1.f, dL);
                    const bool keep = (s_idx[q] != me);   // self-exclusion
                    Fe += keep ? w * dl : 0.f;
                    Ft += keep ? w * dt : 0.f;
                }
            }
        }

        // width-32 butterfly reduce (i is uniform within each 32-lane group)
        Fe += __shfl_xor(Fe, 1);
        Ft += __shfl_xor(Ft, 1);
        Fe += __shfl_xor(Fe, 2);
        Ft += __shfl_xor(Ft, 2);
        Fe += __shfl_xor(Fe, 4);
        Ft += __shfl_xor(Ft, 4);
        Fe += __shfl_xor(Fe, 8);
        Ft += __shfl_xor(Ft, 8);
        Fe += __shfl_xor(Fe, 16);
        Ft += __shfl_xor(Ft, 16);

        if (l32 == 0) {                    // frozen receivers store 0
            out[i]     = Fe;
            out[n + i] = Ft;
        }
    }
}

extern "C" void kernel_launch(void* const* d_in, const int* in_sizes, int n_in,
                              void* d_out, int out_size, void* d_ws, size_t ws_size,
                              hipStream_t stream) {
    const float* ell   = (const float*)d_in[0];
    const float* theta = (const float*)d_in[1];
    const float* fs    = (const float*)d_in[2];
    const float* mass  = (const float*)d_in[3];
    const unsigned char* frozen = (const unsigned char*)d_in[4];
    const int* gsize   = (const int*)d_in[5];
    float* out = (float*)d_out;
    const int n = in_sizes[0];             // assumed <= NMAX (test: 4096)

    const int blocks = (n + RPB - 1) / RPB;   // 128 at n=4096
    gwave_fused<<<blocks, TPB, 0, stream>>>(
        ell, theta, fs, mass, frozen, gsize, n, out);
}

// Round 11
// 16.024 us; speedup vs baseline: 3.7561x; 1.1310x over previous
//
#include <hip/hip_runtime.h>

#define TPB   1024
#define MAXC  1024          // max cells (gs <= 32; test gs = 32); gs >= 4 for wrap
#define SLICE 1024          // tokens per sort slice (= TPB, 1 token/thread)
#define MAXS  8             // g_excl rows reserved (supports n <= 7168: 9*S <= 64)

__device__ __forceinline__ float fpow_pos(float x, float p) {
    // x >= 0; pow via hardware log2/exp2. x==0 -> log2=-inf -> exp2(-inf)=0 (p>0).
    return __builtin_exp2f(p * __builtin_log2f(x));
}

// Node 1: slice counting-sort. Block b sorts tokens [1024b, 1024b+1024) by cell
// using BLOCK-LOCAL LDS counters (no global zeroing -> no third graph node).
// Output: g_pack[b*1024 + pos] (float4: e, theta, fs, idx) slice-sorted by cell,
// g_excl[b][c] = within-slice exclusive start of cell c, g_excl[b][C] = total.
__global__ __launch_bounds__(TPB) void slice_sort(
    const float* __restrict__ ell, const float* __restrict__ theta,
    const float* __restrict__ fs, const unsigned char* __restrict__ frozen,
    const int* __restrict__ gsize_p, int n,
    int* __restrict__ g_excl, float4* __restrict__ g_pack)
{
    __shared__ int s_cnt[MAXC];
    __shared__ int s_wsum[TPB / 64];

    const int tid  = threadIdx.x;
    const int lane = tid & 63;
    const int wid  = tid >> 6;
    const int gs = *gsize_p;
    const int C = gs * gs;                 // <= MAXC <= TPB
    const float TAU = 6.2831855f;          // float32(2*pi)
    const float cw_ell = 2.0f / (float)gs;
    const float cw_th  = TAU  / (float)gs;

    const int slice = blockIdx.x;
    const int base  = slice * SLICE;
    const int r     = base + tid;          // one token per thread

    if (tid < C) s_cnt[tid] = 0;
    __syncthreads();

    // histogram (active tokens only)
    int   c = -1;
    float e = 0.f, t = 0.f, f = 0.f;
    if (r < n && !frozen[r]) {
        e = ell[r]; t = theta[r]; f = fs[r];
        int ce = min(max((int)floorf(e / cw_ell), 0), gs - 1);
        float tw = t - floorf(t / TAU) * TAU;   // jnp.mod(theta, TAU)
        int ct = min(max((int)floorf(tw / cw_th), 0), gs - 1);
        c = ce * gs + ct;
        atomicAdd(&s_cnt[c], 1);
    }
    __syncthreads();

    // exclusive scan of cell counts (wave shuffles + 1 second level)
    const int cnt = (tid < C) ? s_cnt[tid] : 0;
    int v = cnt;
    #pragma unroll
    for (int d = 1; d < 64; d <<= 1) {
        int u = __shfl_up(v, d, 64);
        if (lane >= d) v += u;
    }
    if (lane == 63) s_wsum[wid] = v;
    __syncthreads();
    if (wid == 0) {
        int w = (lane < TPB / 64) ? s_wsum[lane] : 0;
        #pragma unroll
        for (int d = 1; d < TPB / 64; d <<= 1) {
            int u = __shfl_up(w, d, 64);
            if (lane >= d) w += u;
        }
        if (lane < TPB / 64) s_wsum[lane] = w;
    }
    __syncthreads();
    const int excl = v - cnt + ((wid > 0) ? s_wsum[wid - 1] : 0);
    if (tid < C) {
        s_cnt[tid] = excl;                 // scatter cursor (only owner read it)
        g_excl[slice * (MAXC + 1) + tid] = excl;
        if (tid == C - 1) g_excl[slice * (MAXC + 1) + C] = excl + cnt;
    }
    __syncthreads();

    // scatter within the slice region
    if (c >= 0) {
        const int pos = atomicAdd(&s_cnt[c], 1);
        g_pack[base + pos] = make_float4(e, t, f, __int_as_float(r));
    }
}

// Node 2: one 64-lane wave per receiver. The 9-cell neighborhood across S
// slices = 9*S <= 64 segments; lane l owns segment (cell l/S, slice l%S),
// avg ~1 candidate -> critical path ~ one transcendental chain, then a
// 6-step butterfly reduce. Direct store (frozen receivers store 0).
__global__ __launch_bounds__(256) void gwave_force(
    const float* __restrict__ ell, const float* __restrict__ theta,
    const float* __restrict__ fs, const float* __restrict__ mass,
    const unsigned char* __restrict__ frozen,
    const int* __restrict__ gsize_p, int n, int S,
    const int* __restrict__ g_excl, const float4* __restrict__ g_pack,
    float* __restrict__ out)
{
    const float PHI       = 1.61803398875f;
    const float INV_PHI   = 0.61803398875f;
    const float ONE_P_PHI = 2.61803398875f;
    const float TAU  = 6.2831855f;         // float32(2*pi)
    const float PI_F = 3.14159274f;        // float32(pi)
    const float EPS  = 1e-10f;

    const int i    = (blockIdx.x * 256 + threadIdx.x) >> 6;  // receiver = wave
    const int lane = threadIdx.x & 63;
    if (i >= n) return;                    // uniform per wave; no barriers below

    float Fe = 0.f, Ft = 0.f;
    if (!frozen[i]) {
        const int gs = *gsize_p;
        const float cw_ell = 2.0f / (float)gs;
        const float cw_th  = TAU  / (float)gs;

        const float e_i = ell[i], t_i = theta[i];
        const float f_i = fs[i],  m_i = mass[i];
        int ce_i = min(max((int)floorf(e_i / cw_ell), 0), gs - 1);
        float tw = t_i - floorf(t_i / TAU) * TAU;
        int ct_i = min(max((int)floorf(tw / cw_th), 0), gs - 1);
        const float tp = PI_F - t_i;

        if (lane < 9 * S) {
            const int cidx = lane / S;     // 0..8 (S uniform)
            const int s    = lane - cidx * S;
            const int kdiv = cidx / 3;     // 0,1,2
            const int ce = ce_i + kdiv - 1;            // ell cells do NOT wrap
            if (ce >= 0 && ce < gs) {
                int ct = ct_i + (cidx - kdiv * 3) - 1; // theta cells wrap
                if (ct < 0) ct += gs; else if (ct >= gs) ct -= gs;
                const int c = ce * gs + ct;

                const int* ex = g_excl + s * (MAXC + 1);
                const int q0 = ex[c], q1 = ex[c + 1];
                const float4* bp = g_pack + (s << 10); // slice base

                for (int q = q0; q < q1; ++q) {
                    const float4 o = bp[q];
                    const int jdx = __float_as_int(o.w);
                    const float dl = o.x - e_i;
                    // jnp.mod(dtheta+pi, tau)-pi; masked pairs never sit at
                    // the 0/tau rounding boundary (|dtheta| <= 2 cells), so
                    // the predicated wrap equals floor-mod.
                    float x = o.y + tp;                // in (-pi, 3pi)
                    x += (x < 0.f)  ? TAU : 0.f;
                    x -= (x >= TAU) ? TAU : 0.f;
                    const float dt = x - PI_F;

                    const float inner = fpow_pos(fabsf(dl), PHI)
                                      + fpow_pos(fabsf(dt), PHI);
                    const float dL = fpow_pos(inner, INV_PHI) + EPS;
                    const float fm = __fdividef(f_i * o.z,
                                        fpow_pos(dL, ONE_P_PHI) * m_i + EPS);
                    const float w = fm * __fdividef(1.f, dL);
                    const bool keep = (jdx != i);      // self-exclusion
                    Fe += keep ? w * dl : 0.f;
                    Ft += keep ? w * dt : 0.f;
                }
            }
        }
    }

    // full-wave butterfly reduce (inactive lanes contribute 0)
    Fe += __shfl_xor(Fe, 1);
    Ft += __shfl_xor(Ft, 1);
    Fe += __shfl_xor(Fe, 2);
    Ft += __shfl_xor(Ft, 2);
    Fe += __shfl_xor(Fe, 4);
    Ft += __shfl_xor(Ft, 4);
    Fe += __shfl_xor(Fe, 8);
    Ft += __shfl_xor(Ft, 8);
    Fe += __shfl_xor(Fe, 16);
    Ft += __shfl_xor(Ft, 16);
    Fe += __shfl_xor(Fe, 32);
    Ft += __shfl_xor(Ft, 32);

    if (lane == 0) {
        out[i]     = Fe;
        out[n + i] = Ft;
    }
}

extern "C" void kernel_launch(void* const* d_in, const int* in_sizes, int n_in,
                              void* d_out, int out_size, void* d_ws, size_t ws_size,
                              hipStream_t stream) {
    const float* ell   = (const float*)d_in[0];
    const float* theta = (const float*)d_in[1];
    const float* fs    = (const float*)d_in[2];
    const float* mass  = (const float*)d_in[3];
    const unsigned char* frozen = (const unsigned char*)d_in[4];
    const int* gsize   = (const int*)d_in[5];
    float* out = (float*)d_out;
    const int n = in_sizes[0];             // test: 4096 -> S = 4

    const int S = (n + SLICE - 1) / SLICE; // slices (<= MAXS; 9*S <= 64)

    // ws: g_excl[MAXS][MAXC+1] ints (32.8 KB, padded to 33024 B), then g_pack[n]
    int*    g_excl = (int*)d_ws;
    float4* g_pack = (float4*)((char*)d_ws + 33024);

    slice_sort<<<S, TPB, 0, stream>>>(ell, theta, fs, frozen, gsize, n,
                                      g_excl, g_pack);

    const int waves  = n;                  // one wave per receiver
    const int blocks = (waves * 64 + 255) / 256;
    gwave_force<<<blocks, 256, 0, stream>>>(ell, theta, fs, mass, frozen,
                                            gsize, n, S, g_excl, g_pack, out);
}